// Round 5
// baseline (614.544 us; speedup 1.0000x reference)
//
#include <hip/hip_runtime.h>
#include <math.h>

#define NG 128          // graphs
#define NPG 256         // nodes per graph
#define NN 32768        // total nodes
#define HDIM 256        // hidden
#define FIN 128         // input features

// ---------------- CSR build ----------------
__global__ void k_count(const int* __restrict__ dst, int* __restrict__ counts, int E) {
    int e = blockIdx.x * blockDim.x + threadIdx.x;
    if (e < E) atomicAdd(&counts[dst[e]], 1);
}

__global__ void k_scan(const int* __restrict__ counts, int* __restrict__ rowptr) {
    __shared__ int sums[1024];
    int tid = threadIdx.x;
    int base = tid * 32;
    int local[32];
    int s = 0;
#pragma unroll
    for (int j = 0; j < 32; j++) { local[j] = s; s += counts[base + j]; }
    sums[tid] = s;
    __syncthreads();
    for (int off = 1; off < 1024; off <<= 1) {
        int v = (tid >= off) ? sums[tid - off] : 0;
        __syncthreads();
        sums[tid] += v;
        __syncthreads();
    }
    int prev = (tid > 0) ? sums[tid - 1] : 0;
#pragma unroll
    for (int j = 0; j < 32; j++) rowptr[base + j] = prev + local[j];
    if (tid == 1023) rowptr[NN] = sums[1023];
}

__global__ void k_fill(const int* __restrict__ src, const int* __restrict__ dst,
                       const int* __restrict__ rowptr, int* __restrict__ cursor,
                       int* __restrict__ csr_src, int E) {
    int e = blockIdx.x * blockDim.x + threadIdx.x;
    if (e < E) {
        int d = dst[e];
        int p = atomicAdd(&cursor[d], 1);
        csr_src[rowptr[d] + p] = src[e];
    }
}

// canonical order: wave-parallel rank sort of each node's segment by src value
__global__ __launch_bounds__(256) void k_sortw(const int* __restrict__ rowptr, int* __restrict__ csr) {
    int wid = (blockIdx.x * blockDim.x + threadIdx.x) >> 6;
    int lane = threadIdx.x & 63;
    if (wid >= NN) return;
    int e0 = rowptr[wid];
    int d = rowptr[wid + 1] - e0;
    if (d <= 1) return;
    if (d <= 64) {
        int key = (lane < d) ? csr[e0 + lane] : 0x7fffffff;
        int rank = 0;
        for (int j = 0; j < d; j++) {
            int kj = __shfl(key, j);
            rank += (kj < key || (kj == key && j < lane)) ? 1 : 0;
        }
        if (lane < d) csr[e0 + rank] = key;
    } else if (lane == 0) {
        for (int a = e0 + 1; a < e0 + d; a++) {
            int key = csr[a];
            int b = a - 1;
            while (b >= e0 && csr[b] > key) { csr[b + 1] = csr[b]; b--; }
            csr[b + 1] = key;
        }
    }
}

// ---------------- SGEMM: C[list[m] x 256] = A[list[m] x K] @ B[K x 256], f32 ----------------
#define BM 64
#define BN 64
#define BK 16
__global__ __launch_bounds__(256) void k_sgemm(const float* __restrict__ A,
                                               const float* __restrict__ B,
                                               float* __restrict__ C, int K,
                                               const int* __restrict__ list,
                                               const float* __restrict__ brelu) {
    const int N = HDIM;
    __shared__ float As[BK][BM];
    __shared__ float Bs[BK][BN];
    int tid = threadIdx.x;
    int tx = tid & 15, ty = tid >> 4;
    int row0 = blockIdx.y * BM, col0 = blockIdx.x * BN;
    int lm = tid >> 2;
    int arow = list ? list[row0 + lm] : (row0 + lm);
    int crow[4];
#pragma unroll
    for (int i = 0; i < 4; i++) {
        int r = row0 + ty * 4 + i;
        crow[i] = list ? list[r] : r;
    }
    float acc[4][4] = {};
    for (int kb = 0; kb < K; kb += BK) {
        {
            int k = (tid & 3) * 4;
            float4 av = *reinterpret_cast<const float4*>(&A[(size_t)arow * K + kb + k]);
            As[k + 0][lm] = av.x; As[k + 1][lm] = av.y; As[k + 2][lm] = av.z; As[k + 3][lm] = av.w;
        }
        {
            int l = tid * 4;
            int k = l >> 6, c = l & 63;
            *reinterpret_cast<float4*>(&Bs[k][c]) =
                *reinterpret_cast<const float4*>(&B[(size_t)(kb + k) * N + col0 + c]);
        }
        __syncthreads();
#pragma unroll
        for (int k = 0; k < BK; k++) {
            float4 a = *reinterpret_cast<float4*>(&As[k][ty * 4]);
            float4 b = *reinterpret_cast<float4*>(&Bs[k][tx * 4]);
            float av[4] = {a.x, a.y, a.z, a.w};
            float bv[4] = {b.x, b.y, b.z, b.w};
#pragma unroll
            for (int i = 0; i < 4; i++)
#pragma unroll
                for (int j = 0; j < 4; j++) acc[i][j] += av[i] * bv[j];
        }
        __syncthreads();
    }
    float4 bb = make_float4(0.f, 0.f, 0.f, 0.f);
    if (brelu) bb = *reinterpret_cast<const float4*>(&brelu[col0 + tx * 4]);
#pragma unroll
    for (int i = 0; i < 4; i++) {
        float4 v = make_float4(acc[i][0], acc[i][1], acc[i][2], acc[i][3]);
        if (brelu) {
            v.x = fmaxf(v.x + bb.x, 0.f);
            v.y = fmaxf(v.y + bb.y, 0.f);
            v.z = fmaxf(v.z + bb.z, 0.f);
            v.w = fmaxf(v.w + bb.w, 0.f);
        }
        *reinterpret_cast<float4*>(&C[(size_t)crow[i] * N + col0 + tx * 4]) = v;
    }
}

// ---------------- stage 1 aggregation: block per graph, x slice in LDS ----------------
// xa = D^{-1/2}(A+I)D^{-1/2} x ; all nodes active: dis = rsqrt(1+deg)
__global__ __launch_bounds__(256) void k_aggx(const float* __restrict__ x,
                                              const int* __restrict__ rowptr,
                                              const int* __restrict__ csr,
                                              float* __restrict__ xa) {
    __shared__ float xr[NPG][FIN];     // 128 KB
    __shared__ float disv[NPG];
    int g = blockIdx.x, tid = threadIdx.x;
    int lane = tid & 63, wv = tid >> 6;
    {
        int n = g * NPG + tid;
        disv[tid] = rsqrtf((float)(1 + rowptr[n + 1] - rowptr[n]));
    }
    for (int li = tid; li < NPG * (FIN / 4); li += 256) {
        int r = li >> 5, c = li & 31;
        float4 v = *reinterpret_cast<const float4*>(&x[(size_t)(g * NPG + r) * FIN + c * 4]);
        *reinterpret_cast<float4*>(&xr[r][c * 4]) = v;
    }
    __syncthreads();
    for (int l = wv; l < NPG; l += 4) {
        float di = disv[l];
        float self = di * di;
        float2 h = *reinterpret_cast<float2*>(&xr[l][lane * 2]);
        float ax = h.x * self, ay = h.y * self;
        int n = g * NPG + l;
        int e0 = rowptr[n], e1 = rowptr[n + 1];
        for (int e = e0; e < e1; e++) {
            int sr = csr[e] & (NPG - 1);
            float w = disv[sr] * di;
            float2 hs = *reinterpret_cast<float2*>(&xr[sr][lane * 2]);
            ax += hs.x * w; ay += hs.y * w;
        }
        float2 o; o.x = ax; o.y = ay;
        *reinterpret_cast<float2*>(&xa[(size_t)n * FIN + lane * 2]) = o;
    }
}

// ---------------- stage 1 pool: dots + score + topk + poolout, block per graph ----------------
__global__ __launch_bounds__(256) void k_pool1(float* __restrict__ hcur,
                                               const int* __restrict__ rowptr,
                                               const int* __restrict__ csr,
                                               const float* __restrict__ w_rel,
                                               const float* __restrict__ b_rel,
                                               const float* __restrict__ w_root,
                                               int* __restrict__ list_out,
                                               float* __restrict__ z) {
    __shared__ float rrel[NPG];
    __shared__ float scores[NPG];
    __shared__ int pref[NPG];
    __shared__ int newl[128];
    __shared__ float tvv[NPG];
    int g = blockIdx.x, tid = threadIdx.x;
    int lane = tid & 63, wv = tid >> 6;
    float4 wr = *reinterpret_cast<const float4*>(&w_rel[lane * 4]);
    float4 wo = *reinterpret_cast<const float4*>(&w_root[lane * 4]);
    float brel = b_rel[0];
    for (int l = wv; l < NPG; l += 4) {
        float4 h = *reinterpret_cast<const float4*>(&hcur[(size_t)(g * NPG + l) * HDIM + lane * 4]);
        float s1 = h.x * wr.x + h.y * wr.y + h.z * wr.z + h.w * wr.w;
        float s2 = h.x * wo.x + h.y * wo.y + h.z * wo.z + h.w * wo.w;
        for (int off = 32; off > 0; off >>= 1) {
            s1 += __shfl_down(s1, off);
            s2 += __shfl_down(s2, off);
        }
        if (lane == 0) { rrel[l] = s1; scores[l] = s2 + brel; }
    }
    __syncthreads();
    {
        int n = g * NPG + tid;
        float s = scores[tid];
        int e0 = rowptr[n], e1 = rowptr[n + 1];
        for (int e = e0; e < e1; e++) s += rrel[csr[e] & (NPG - 1)];
        scores[tid] = s;
    }
    __syncthreads();
    float my = scores[tid];
    int cnt = 0;
    for (int j = 0; j < NPG; j++) {
        float v = scores[j];
        cnt += (v > my || (v == my && j < tid)) ? 1 : 0;
    }
    int sel = (cnt < 128) ? 1 : 0;
    pref[tid] = sel;
    tvv[tid] = sel ? tanhf(my) : 0.f;
    __syncthreads();
    for (int off = 1; off < NPG; off <<= 1) {
        int v = (tid >= off) ? pref[tid - off] : 0;
        __syncthreads();
        pref[tid] += v;
        __syncthreads();
    }
    if (sel) {
        int rk = pref[tid] - 1;
        newl[rk] = tid;
        list_out[g * 128 + rk] = g * NPG + tid;
    }
    __syncthreads();
    {
        int f = tid;
        float s = 0.f, mx = -INFINITY;
        for (int idx = 0; idx < 128; idx++) {
            int l = newl[idx];
            size_t p = (size_t)(g * NPG + l) * HDIM + f;
            float v = hcur[p] * tvv[l];
            hcur[p] = v;
            s += v;
            mx = fmaxf(mx, v);
        }
        z[g * 768 + f] = s * (1.0f / 128.0f);
        z[g * 768 + 256 + f] = mx;
        z[g * 768 + 512 + f] = s;
    }
}

// ---------------- fused stage (2/3): dis + GCN agg + score + topk + poolout ----------------
template<int KIN, int KOUT>
__global__ __launch_bounds__(256) void k_stage(const float* __restrict__ hW,
                                               const int* __restrict__ rowptr,
                                               const int* __restrict__ csr,
                                               const float* __restrict__ bias,
                                               const float* __restrict__ w_rel,
                                               const float* __restrict__ b_rel,
                                               const float* __restrict__ w_root,
                                               const int* __restrict__ list_in,
                                               int* __restrict__ list_out,
                                               float* __restrict__ hcur,
                                               float* __restrict__ z, float invk) {
    __shared__ float rows[KIN][HDIM];     // KIN KB
    __shared__ int   pos[NPG];
    __shared__ int   lidx[KIN];
    __shared__ float disv[NPG];
    __shared__ float rrel[NPG];
    __shared__ float scores[NPG];
    __shared__ int   pref[NPG];
    __shared__ int   newl[KOUT];
    __shared__ float tvv[NPG];
    int g = blockIdx.x, tid = threadIdx.x;
    int lane = tid & 63, wv = tid >> 6;

    pos[tid] = -1;
    scores[tid] = -INFINITY;
    disv[tid] = 0.f;
    __syncthreads();
    if (tid < KIN) {
        int node = list_in[g * KIN + tid];
        int l = node & (NPG - 1);
        lidx[tid] = l;
        pos[l] = tid;
    }
    __syncthreads();
    // dis (active in-degree) for actives
    if (tid < KIN) {
        int l = lidx[tid];
        int n = g * NPG + l;
        int e0 = rowptr[n], e1 = rowptr[n + 1];
        int cnt = 1;
        for (int e = e0; e < e1; e++) cnt += (pos[csr[e] & (NPG - 1)] >= 0) ? 1 : 0;
        disv[l] = rsqrtf((float)cnt);
    }
    // stage hW rows of actives into LDS
    for (int li = tid; li < KIN * (HDIM / 4); li += 256) {
        int r = li >> 6, c = li & 63;
        float4 v = *reinterpret_cast<const float4*>(&hW[(size_t)(g * NPG + lidx[r]) * HDIM + c * 4]);
        *reinterpret_cast<float4*>(&rows[r][c * 4]) = v;
    }
    __syncthreads();

    float4 bb = *reinterpret_cast<const float4*>(&bias[lane * 4]);
    float4 wr = *reinterpret_cast<const float4*>(&w_rel[lane * 4]);
    float4 wo = *reinterpret_cast<const float4*>(&w_root[lane * 4]);
    float brel = b_rel[0];

    // aggregate per active dst (wave per dst)
    for (int j = wv; j < KIN; j += 4) {
        int l = lidx[j];
        float di = disv[l];
        float self = di * di;
        float4 r0 = *reinterpret_cast<float4*>(&rows[j][lane * 4]);
        float ax = r0.x * self, ay = r0.y * self, az = r0.z * self, aw = r0.w * self;
        int n = g * NPG + l;
        int e0 = rowptr[n], e1 = rowptr[n + 1];
        for (int e = e0; e < e1; e++) {
            int sr = csr[e] & (NPG - 1);
            int slot = pos[sr];
            if (slot >= 0) {
                float w = disv[sr] * di;
                float4 rs = *reinterpret_cast<float4*>(&rows[slot][lane * 4]);
                ax += rs.x * w; ay += rs.y * w; az += rs.z * w; aw += rs.w * w;
            }
        }
        float4 o;
        o.x = fmaxf(ax + bb.x, 0.f);
        o.y = fmaxf(ay + bb.y, 0.f);
        o.z = fmaxf(az + bb.z, 0.f);
        o.w = fmaxf(aw + bb.w, 0.f);
        *reinterpret_cast<float4*>(&hcur[(size_t)n * HDIM + lane * 4]) = o;
        float s1 = o.x * wr.x + o.y * wr.y + o.z * wr.z + o.w * wr.w;
        float s2 = o.x * wo.x + o.y * wo.y + o.z * wo.z + o.w * wo.w;
        for (int off = 32; off > 0; off >>= 1) {
            s1 += __shfl_down(s1, off);
            s2 += __shfl_down(s2, off);
        }
        if (lane == 0) { rrel[l] = s1; scores[l] = s2 + brel; }
    }
    __syncthreads();
    // score gather
    if (tid < KIN) {
        int l = lidx[tid];
        int n = g * NPG + l;
        float s = scores[l];
        int e0 = rowptr[n], e1 = rowptr[n + 1];
        for (int e = e0; e < e1; e++) {
            int sr = csr[e] & (NPG - 1);
            if (pos[sr] >= 0) s += rrel[sr];
        }
        scores[l] = s;
    }
    __syncthreads();
    // stable top-KOUT
    float my = scores[tid];
    int cnt = 0;
    for (int j = 0; j < NPG; j++) {
        float v = scores[j];
        cnt += (v > my || (v == my && j < tid)) ? 1 : 0;
    }
    int sel = (cnt < KOUT) ? 1 : 0;
    pref[tid] = sel;
    tvv[tid] = sel ? tanhf(my) : 0.f;
    __syncthreads();
    for (int off = 1; off < NPG; off <<= 1) {
        int v = (tid >= off) ? pref[tid - off] : 0;
        __syncthreads();
        pref[tid] += v;
        __syncthreads();
    }
    if (sel) {
        int rk = pref[tid] - 1;
        newl[rk] = tid;
        list_out[g * KOUT + rk] = g * NPG + tid;
    }
    __syncthreads();
    // poolout + readout accumulate
    {
        int f = tid;
        float s = 0.f, mx = -INFINITY;
        for (int idx = 0; idx < KOUT; idx++) {
            int l = newl[idx];
            size_t p = (size_t)(g * NPG + l) * HDIM + f;
            float v = hcur[p] * tvv[l];
            hcur[p] = v;
            s += v;
            mx = fmaxf(mx, v);
        }
        z[g * 768 + f] += s * invk;
        z[g * 768 + 256 + f] += mx;
        z[g * 768 + 512 + f] += s;
    }
}

// ---------------- final MLP + log_softmax, block per graph ----------------
__global__ __launch_bounds__(256) void k_mlp(const float* __restrict__ z,
                                             const float* __restrict__ W1, const float* __restrict__ b1,
                                             const float* __restrict__ W2, const float* __restrict__ b2,
                                             const float* __restrict__ W3, const float* __restrict__ b3,
                                             float* __restrict__ out) {
    __shared__ float zb[768];
    __shared__ float t1[256];
    __shared__ float t2[128];
    __shared__ float t3[10];
    __shared__ float lse;
    int g = blockIdx.x, tid = threadIdx.x;
    zb[tid] = z[g * 768 + tid];
    zb[tid + 256] = z[g * 768 + 256 + tid];
    zb[tid + 512] = z[g * 768 + 512 + tid];
    __syncthreads();
    {
        float s = b1[tid];
        for (int i = 0; i < 768; i++) s += zb[i] * W1[(size_t)i * 256 + tid];
        t1[tid] = fmaxf(s, 0.f);
    }
    __syncthreads();
    if (tid < 128) {
        float s = b2[tid];
        for (int i = 0; i < 256; i++) s += t1[i] * W2[(size_t)i * 128 + tid];
        t2[tid] = fmaxf(s, 0.f);
    }
    __syncthreads();
    if (tid < 10) {
        float s = b3[tid];
        for (int i = 0; i < 128; i++) s += t2[i] * W3[(size_t)i * 10 + tid];
        t3[tid] = s;
    }
    __syncthreads();
    if (tid == 0) {
        float m = t3[0];
        for (int c = 1; c < 10; c++) m = fmaxf(m, t3[c]);
        float se = 0.f;
        for (int c = 0; c < 10; c++) se += expf(t3[c] - m);
        lse = m + logf(se);
    }
    __syncthreads();
    if (tid < 10) out[g * 10 + tid] = t3[tid] - lse;
}

// ---------------- launcher ----------------
extern "C" void kernel_launch(void* const* d_in, const int* in_sizes, int n_in,
                              void* d_out, int out_size, void* d_ws, size_t ws_size,
                              hipStream_t stream) {
    const float* x        = (const float*)d_in[0];
    const int*   ei       = (const int*)d_in[1];
    const float* conv1_W  = (const float*)d_in[3];
    const float* conv1_b  = (const float*)d_in[4];
    const float* conv2_W  = (const float*)d_in[5];
    const float* conv2_b  = (const float*)d_in[6];
    const float* conv3_W  = (const float*)d_in[7];
    const float* conv3_b  = (const float*)d_in[8];
    const float* p1_relW  = (const float*)d_in[9];
    const float* p1_relb  = (const float*)d_in[10];
    const float* p1_rootW = (const float*)d_in[11];
    const float* p2_relW  = (const float*)d_in[12];
    const float* p2_relb  = (const float*)d_in[13];
    const float* p2_rootW = (const float*)d_in[14];
    const float* fc1_W    = (const float*)d_in[15];
    const float* fc1_b    = (const float*)d_in[16];
    const float* fc2_W    = (const float*)d_in[17];
    const float* fc2_b    = (const float*)d_in[18];
    const float* fc3_W    = (const float*)d_in[19];
    const float* fc3_b    = (const float*)d_in[20];
    float* out = (float*)d_out;

    const int E = in_sizes[1] / 2;
    const int* e_src = ei;
    const int* e_dst = ei + E;

    // workspace layout
    char* base = (char*)d_ws;
    size_t off = 0;
    auto alloc = [&](size_t bytes) { size_t o = off; off = (off + bytes + 255) & ~(size_t)255; return o; };
    float* hW     = (float*)(base + alloc((size_t)NN * HDIM * 4));   // also xa (NN x FIN)
    float* hcur   = (float*)(base + alloc((size_t)NN * HDIM * 4));
    int*   rowptr = (int*)(base + alloc((NN + 1) * 4));
    int*   counts = (int*)(base + alloc(NN * 4));
    int*   cursor = (int*)(base + alloc(NN * 4));
    int*   csr    = (int*)(base + alloc((size_t)E * 4));
    float* z      = (float*)(base + alloc((size_t)NG * 768 * 4));
    int*   list1  = (int*)(base + alloc((size_t)NG * 128 * 4));
    int*   list2  = (int*)(base + alloc((size_t)NG * 64 * 4));
    int*   list3  = (int*)(base + alloc((size_t)NG * 32 * 4));

    hipMemsetAsync(counts, 0, NN * 4, stream);
    hipMemsetAsync(cursor, 0, NN * 4, stream);

    // CSR build (canonical sorted-by-src order => deterministic)
    int eblocks = (E + 255) / 256;
    k_count<<<eblocks, 256, 0, stream>>>(e_dst, counts, E);
    k_scan<<<1, 1024, 0, stream>>>(counts, rowptr);
    k_fill<<<eblocks, 256, 0, stream>>>(e_src, e_dst, rowptr, cursor, csr, E);
    k_sortw<<<NN * 64 / 256, 256, 0, stream>>>(rowptr, csr);

    float* xa = hW;

    // ---- stage 1 ----
    k_aggx<<<NG, 256, 0, stream>>>(x, rowptr, csr, xa);
    {
        dim3 ggrid(HDIM / BN, NN / BM);
        k_sgemm<<<ggrid, 256, 0, stream>>>(xa, conv1_W, hcur, FIN, nullptr, conv1_b);
    }
    k_pool1<<<NG, 256, 0, stream>>>(hcur, rowptr, csr, p1_relW, p1_relb, p1_rootW, list1, z);

    // ---- stage 2 ----
    {
        dim3 ggrid(HDIM / BN, (NG * 128) / BM);
        k_sgemm<<<ggrid, 256, 0, stream>>>(hcur, conv2_W, hW, HDIM, list1, nullptr);
    }
    k_stage<128, 64><<<NG, 256, 0, stream>>>(hW, rowptr, csr, conv2_b, p2_relW, p2_relb,
                                             p2_rootW, list1, list2, hcur, z, 1.0f / 64.0f);

    // ---- stage 3 ----
    {
        dim3 ggrid(HDIM / BN, (NG * 64) / BM);
        k_sgemm<<<ggrid, 256, 0, stream>>>(hcur, conv3_W, hW, HDIM, list2, nullptr);
    }
    k_stage<64, 32><<<NG, 256, 0, stream>>>(hW, rowptr, csr, conv3_b, p2_relW, p2_relb,
                                            p2_rootW, list2, list3, hcur, z, 1.0f / 32.0f);

    k_mlp<<<NG, 256, 0, stream>>>(z, fc1_W, fc1_b, fc2_W, fc2_b, fc3_W, fc3_b, out);
}

// Round 6
// 360.603 us; speedup vs baseline: 1.7042x; 1.7042x over previous
//
#include <hip/hip_runtime.h>
#include <math.h>

#define NG 128          // graphs
#define NPG 256         // nodes per graph
#define NN 32768        // total nodes
#define HDIM 256        // hidden
#define FIN 128         // input features

// ---------------- CSR build: block per graph, LDS counting sort ----------------
// edges are grouped by graph (EPG per graph, all intra-graph)
__global__ __launch_bounds__(256) void k_csr(const int* __restrict__ esrc,
                                             const int* __restrict__ edst, int EPG,
                                             int* __restrict__ rowptr, int* __restrict__ csr) {
    __shared__ int cnt[NPG];
    __shared__ int pref[NPG];
    __shared__ int cur[NPG];
    int g = blockIdx.x, tid = threadIdx.x;
    cnt[tid] = 0;
    __syncthreads();
    int base = g * EPG;
    for (int e = base + tid; e < base + EPG; e += 256)
        atomicAdd(&cnt[edst[e] & (NPG - 1)], 1);
    __syncthreads();
    int v = cnt[tid];
    pref[tid] = v;
    __syncthreads();
    for (int off = 1; off < NPG; off <<= 1) {
        int t = (tid >= off) ? pref[tid - off] : 0;
        __syncthreads();
        pref[tid] += t;
        __syncthreads();
    }
    int excl = pref[tid] - v;
    rowptr[g * NPG + tid] = base + excl;
    cur[tid] = base + excl;
    if (g == 0 && tid == 0) rowptr[NN] = NG * EPG;
    __syncthreads();
    for (int e = base + tid; e < base + EPG; e += 256) {
        int d = edst[e] & (NPG - 1);
        int p = atomicAdd(&cur[d], 1);
        csr[p] = esrc[e];
    }
}

// canonical order: wave-parallel rank sort of each node's segment by src value
__global__ __launch_bounds__(256) void k_sortw(const int* __restrict__ rowptr, int* __restrict__ csr) {
    int wid = (blockIdx.x * blockDim.x + threadIdx.x) >> 6;
    int lane = threadIdx.x & 63;
    if (wid >= NN) return;
    int e0 = rowptr[wid];
    int d = rowptr[wid + 1] - e0;
    if (d <= 1) return;
    if (d <= 64) {
        int key = (lane < d) ? csr[e0 + lane] : 0x7fffffff;
        int rank = 0;
        for (int j = 0; j < d; j++) {
            int kj = __shfl(key, j);
            rank += (kj < key || (kj == key && j < lane)) ? 1 : 0;
        }
        if (lane < d) csr[e0 + rank] = key;
    } else if (lane == 0) {
        for (int a = e0 + 1; a < e0 + d; a++) {
            int key = csr[a];
            int b = a - 1;
            while (b >= e0 && csr[b] > key) { csr[b + 1] = csr[b]; b--; }
            csr[b + 1] = key;
        }
    }
}

// ---------------- SGEMM: C[list[m] x 256] = A[list[m] x K] @ B[K x 256], f32 ----------------
#define BM 64
#define BN 64
#define BK 16
__global__ __launch_bounds__(256) void k_sgemm(const float* __restrict__ A,
                                               const float* __restrict__ B,
                                               float* __restrict__ C, int K,
                                               const int* __restrict__ list,
                                               const float* __restrict__ brelu) {
    const int N = HDIM;
    __shared__ float As[BK][BM];
    __shared__ float Bs[BK][BN];
    int tid = threadIdx.x;
    int tx = tid & 15, ty = tid >> 4;
    int row0 = blockIdx.y * BM, col0 = blockIdx.x * BN;
    int lm = tid >> 2;
    int arow = list ? list[row0 + lm] : (row0 + lm);
    int crow[4];
#pragma unroll
    for (int i = 0; i < 4; i++) {
        int r = row0 + ty * 4 + i;
        crow[i] = list ? list[r] : r;
    }
    float acc[4][4] = {};
    for (int kb = 0; kb < K; kb += BK) {
        {
            int k = (tid & 3) * 4;
            float4 av = *reinterpret_cast<const float4*>(&A[(size_t)arow * K + kb + k]);
            As[k + 0][lm] = av.x; As[k + 1][lm] = av.y; As[k + 2][lm] = av.z; As[k + 3][lm] = av.w;
        }
        {
            int l = tid * 4;
            int k = l >> 6, c = l & 63;
            *reinterpret_cast<float4*>(&Bs[k][c]) =
                *reinterpret_cast<const float4*>(&B[(size_t)(kb + k) * N + col0 + c]);
        }
        __syncthreads();
#pragma unroll
        for (int k = 0; k < BK; k++) {
            float4 a = *reinterpret_cast<float4*>(&As[k][ty * 4]);
            float4 b = *reinterpret_cast<float4*>(&Bs[k][tx * 4]);
            float av[4] = {a.x, a.y, a.z, a.w};
            float bv[4] = {b.x, b.y, b.z, b.w};
#pragma unroll
            for (int i = 0; i < 4; i++)
#pragma unroll
                for (int j = 0; j < 4; j++) acc[i][j] += av[i] * bv[j];
        }
        __syncthreads();
    }
    float4 bb = make_float4(0.f, 0.f, 0.f, 0.f);
    if (brelu) bb = *reinterpret_cast<const float4*>(&brelu[col0 + tx * 4]);
#pragma unroll
    for (int i = 0; i < 4; i++) {
        float4 v = make_float4(acc[i][0], acc[i][1], acc[i][2], acc[i][3]);
        if (brelu) {
            v.x = fmaxf(v.x + bb.x, 0.f);
            v.y = fmaxf(v.y + bb.y, 0.f);
            v.z = fmaxf(v.z + bb.z, 0.f);
            v.w = fmaxf(v.w + bb.w, 0.f);
        }
        *reinterpret_cast<float4*>(&C[(size_t)crow[i] * N + col0 + tx * 4]) = v;
    }
}

// ---------------- per-stage kernels ----------------
// stage-1 dis (all active): rsqrt(1+deg) straight from rowptr
__global__ void k_dis1(const int* __restrict__ rowptr, float* __restrict__ dis) {
    int i = blockIdx.x * blockDim.x + threadIdx.x;
    if (i < NN) dis[i] = rsqrtf((float)(1 + rowptr[i + 1] - rowptr[i]));
}

// masked dis for stages 2/3
__global__ void k_dis(const float* __restrict__ nmask, const int* __restrict__ rowptr,
                      const int* __restrict__ csr, float* __restrict__ dis) {
    int i = blockIdx.x * blockDim.x + threadIdx.x;
    if (i >= NN) return;
    if (nmask[i] <= 0.f) { dis[i] = 0.f; return; }
    int e0 = rowptr[i], e1 = rowptr[i + 1];
    int cnt = 1;
    for (int e = e0; e < e1; e++) cnt += (nmask[csr[e]] > 0.f) ? 1 : 0;
    dis[i] = rsqrtf((float)cnt);
}

// per-edge weight stream: w[e] = dis[src]*dis[dst] (only rows of active dst written)
__global__ void k_wedge(const float* __restrict__ dis, const int* __restrict__ rowptr,
                        const int* __restrict__ csr, float* __restrict__ w) {
    int i = blockIdx.x * blockDim.x + threadIdx.x;
    if (i >= NN) return;
    float di = dis[i];
    if (di <= 0.f) return;
    int e0 = rowptr[i], e1 = rowptr[i + 1];
    for (int e = e0; e < e1; e++) w[e] = dis[csr[e]] * di;
}

// XCD-locality swizzle: all blocks of one graph land on one XCD's L2
__device__ __forceinline__ int swz_block(int bid, int bpg) {
    int xcd = bid & 7, r = bid >> 3;
    int graph = xcd * (NG / 8) + r / bpg;
    int sub = r - (r / bpg) * bpg;
    return graph * bpg + sub;
}

// stage 1: xa = D^{-1/2}(A+I)D^{-1/2} x ; half-wave (32 lanes x float4) per node
__global__ __launch_bounds__(256) void k_aggx(const float* __restrict__ x,
                                              const float* __restrict__ dis,
                                              const int* __restrict__ rowptr,
                                              const int* __restrict__ csr,
                                              const float* __restrict__ wedge,
                                              float* __restrict__ xa) {
    int blk = swz_block(blockIdx.x, NPG / 8);
    int n = blk * 8 + (threadIdx.x >> 5);
    int lane = threadIdx.x & 31;
    const float4* xp = reinterpret_cast<const float4*>(x);
    float di = dis[n];
    float4 h = xp[(size_t)n * (FIN / 4) + lane];
    float self = di * di;
    float ax = h.x * self, ay = h.y * self, az = h.z * self, aw = h.w * self;
    int e0 = rowptr[n], e1 = rowptr[n + 1];
    for (int e = e0; e < e1; e++) {
        int s = csr[e];
        float w = wedge[e];
        float4 hs = xp[(size_t)s * (FIN / 4) + lane];
        ax += hs.x * w; ay += hs.y * w; az += hs.z * w; aw += hs.w * w;
    }
    float4 o = make_float4(ax, ay, az, aw);
    reinterpret_cast<float4*>(xa)[(size_t)n * (FIN / 4) + lane] = o;
}

// wave per node: r_rel = h . w_rel, r_root = h . w_root (stage 1)
__global__ __launch_bounds__(256) void k_dots(const float* __restrict__ h,
                                              const float* __restrict__ w_rel,
                                              const float* __restrict__ w_root,
                                              float* __restrict__ r_rel,
                                              float* __restrict__ r_root) {
    int wid = (blockIdx.x * blockDim.x + threadIdx.x) >> 6;
    int lane = threadIdx.x & 63;
    if (wid >= NN) return;
    float4 hv = *reinterpret_cast<const float4*>(&h[(size_t)wid * HDIM + lane * 4]);
    float4 wr = *reinterpret_cast<const float4*>(&w_rel[lane * 4]);
    float4 wo = *reinterpret_cast<const float4*>(&w_root[lane * 4]);
    float s1 = hv.x * wr.x + hv.y * wr.y + hv.z * wr.z + hv.w * wr.w;
    float s2 = hv.x * wo.x + hv.y * wo.y + hv.z * wo.z + hv.w * wo.w;
    for (int off = 32; off > 0; off >>= 1) {
        s1 += __shfl_down(s1, off);
        s2 += __shfl_down(s2, off);
    }
    if (lane == 0) { r_rel[wid] = s1; r_root[wid] = s2; }
}

// stages 2/3: wave per ACTIVE node, gather on hW, fused bias+relu+score dots
__global__ __launch_bounds__(256) void k_gcn_agg(const float* __restrict__ hW,
                                                 const float* __restrict__ dis,
                                                 const int* __restrict__ rowptr,
                                                 const int* __restrict__ csr,
                                                 const float* __restrict__ wedge,
                                                 const float* __restrict__ bias,
                                                 const int* __restrict__ list, int bpg,
                                                 const float* __restrict__ w_rel,
                                                 const float* __restrict__ w_root,
                                                 float* __restrict__ out,
                                                 float* __restrict__ r_rel,
                                                 float* __restrict__ r_root) {
    int blk = swz_block(blockIdx.x, bpg);
    int idx = blk * 4 + (threadIdx.x >> 6);
    int lane = threadIdx.x & 63;
    int wid = list[idx];
    float di = dis[wid];
    float4 h = *reinterpret_cast<const float4*>(&hW[(size_t)wid * HDIM + lane * 4]);
    float self = di * di;
    float ax = h.x * self, ay = h.y * self, az = h.z * self, aw = h.w * self;
    int e0 = rowptr[wid], e1 = rowptr[wid + 1];
    for (int e = e0; e < e1; e++) {
        float w = wedge[e];
        if (w > 0.f) {
            int s = csr[e];
            float4 hs = *reinterpret_cast<const float4*>(&hW[(size_t)s * HDIM + lane * 4]);
            ax += hs.x * w; ay += hs.y * w; az += hs.z * w; aw += hs.w * w;
        }
    }
    float4 b = *reinterpret_cast<const float4*>(&bias[lane * 4]);
    float4 o;
    o.x = fmaxf(ax + b.x, 0.f);
    o.y = fmaxf(ay + b.y, 0.f);
    o.z = fmaxf(az + b.z, 0.f);
    o.w = fmaxf(aw + b.w, 0.f);
    *reinterpret_cast<float4*>(&out[(size_t)wid * HDIM + lane * 4]) = o;
    float4 wr = *reinterpret_cast<const float4*>(&w_rel[lane * 4]);
    float4 wo = *reinterpret_cast<const float4*>(&w_root[lane * 4]);
    float s1 = o.x * wr.x + o.y * wr.y + o.z * wr.z + o.w * wr.w;
    float s2 = o.x * wo.x + o.y * wo.y + o.z * wo.z + o.w * wo.w;
    for (int off = 32; off > 0; off >>= 1) {
        s1 += __shfl_down(s1, off);
        s2 += __shfl_down(s2, off);
    }
    if (lane == 0) { r_rel[wid] = s1; r_root[wid] = s2; }
}

// score gather; active ⟺ dis>0
__global__ void k_score(const float* __restrict__ dis, const int* __restrict__ rowptr,
                        const int* __restrict__ csr, const float* __restrict__ r_rel,
                        const float* __restrict__ r_root, const float* __restrict__ b_rel,
                        float* __restrict__ score) {
    int i = blockIdx.x * blockDim.x + threadIdx.x;
    if (i >= NN) return;
    if (dis[i] <= 0.f) { score[i] = -INFINITY; return; }
    float s = b_rel[0] + r_root[i];
    int e0 = rowptr[i], e1 = rowptr[i + 1];
    for (int e = e0; e < e1; e++) {
        int src = csr[e];
        if (dis[src] > 0.f) s += r_rel[src];
    }
    score[i] = s;
}

// block per graph: stable top-k (rank counting) -> nmask + deterministic active list
__global__ __launch_bounds__(256) void k_topk(const float* __restrict__ score, int k,
                                              float* __restrict__ nmask,
                                              int* __restrict__ list) {
    __shared__ float sc[NPG];
    __shared__ int pref[NPG];
    int g = blockIdx.x, tid = threadIdx.x;
    float my = score[g * NPG + tid];
    sc[tid] = my;
    __syncthreads();
    int cnt = 0;
    for (int j = 0; j < NPG; j++) {
        float v = sc[j];
        cnt += (v > my || (v == my && j < tid)) ? 1 : 0;
    }
    int a = (cnt < k) ? 1 : 0;
    nmask[g * NPG + tid] = (float)a;
    pref[tid] = a;
    __syncthreads();
    for (int off = 1; off < NPG; off <<= 1) {
        int v = (tid >= off) ? pref[tid - off] : 0;
        __syncthreads();
        pref[tid] += v;
        __syncthreads();
    }
    if (a) list[g * k + pref[tid] - 1] = g * NPG + tid;
}

// grid = NG*4: block = (graph, 64-feature chunk); 256 thr = 64 feat x 4 node-partitions
__global__ __launch_bounds__(256) void k_poolout2(float* __restrict__ h,
                                                  const float* __restrict__ score,
                                                  const int* __restrict__ list, int k,
                                                  float invk, float* __restrict__ z) {
    __shared__ float tv[128];        // k <= 128
    __shared__ float red_s[4][64];
    __shared__ float red_m[4][64];
    int g = blockIdx.x >> 2, fc = blockIdx.x & 3;
    int tid = threadIdx.x;
    int x = tid & 63, y = tid >> 6;
    if (tid < k) tv[tid] = tanhf(score[list[g * k + tid]]);
    __syncthreads();
    int f = fc * 64 + x;
    float s = 0.f, mx = -INFINITY;
    for (int idx = y; idx < k; idx += 4) {
        int node = list[g * k + idx];
        size_t p = (size_t)node * HDIM + f;
        float v = h[p] * tv[idx];
        h[p] = v;
        s += v;
        mx = fmaxf(mx, v);
    }
    red_s[y][x] = s;
    red_m[y][x] = mx;
    __syncthreads();
    if (y == 0) {
        s = red_s[0][x] + red_s[1][x] + red_s[2][x] + red_s[3][x];
        mx = fmaxf(fmaxf(red_m[0][x], red_m[1][x]), fmaxf(red_m[2][x], red_m[3][x]));
        z[g * 768 + f] += s * invk;
        z[g * 768 + 256 + f] += mx;
        z[g * 768 + 512 + f] += s;
    }
}

// ---------------- final MLP + log_softmax, block per graph ----------------
__global__ __launch_bounds__(256) void k_mlp(const float* __restrict__ z,
                                             const float* __restrict__ W1, const float* __restrict__ b1,
                                             const float* __restrict__ W2, const float* __restrict__ b2,
                                             const float* __restrict__ W3, const float* __restrict__ b3,
                                             float* __restrict__ out) {
    __shared__ float zb[768];
    __shared__ float t1[256];
    __shared__ float t2[128];
    __shared__ float t3[10];
    __shared__ float lse;
    int g = blockIdx.x, tid = threadIdx.x;
    zb[tid] = z[g * 768 + tid];
    zb[tid + 256] = z[g * 768 + 256 + tid];
    zb[tid + 512] = z[g * 768 + 512 + tid];
    __syncthreads();
    {
        float s = b1[tid];
        for (int i = 0; i < 768; i++) s += zb[i] * W1[(size_t)i * 256 + tid];
        t1[tid] = fmaxf(s, 0.f);
    }
    __syncthreads();
    if (tid < 128) {
        float s = b2[tid];
        for (int i = 0; i < 256; i++) s += t1[i] * W2[(size_t)i * 128 + tid];
        t2[tid] = fmaxf(s, 0.f);
    }
    __syncthreads();
    if (tid < 10) {
        float s = b3[tid];
        for (int i = 0; i < 128; i++) s += t2[i] * W3[(size_t)i * 10 + tid];
        t3[tid] = s;
    }
    __syncthreads();
    if (tid == 0) {
        float m = t3[0];
        for (int c = 1; c < 10; c++) m = fmaxf(m, t3[c]);
        float se = 0.f;
        for (int c = 0; c < 10; c++) se += expf(t3[c] - m);
        lse = m + logf(se);
    }
    __syncthreads();
    if (tid < 10) out[g * 10 + tid] = t3[tid] - lse;
}

// ---------------- launcher ----------------
extern "C" void kernel_launch(void* const* d_in, const int* in_sizes, int n_in,
                              void* d_out, int out_size, void* d_ws, size_t ws_size,
                              hipStream_t stream) {
    const float* x        = (const float*)d_in[0];
    const int*   ei       = (const int*)d_in[1];
    const float* conv1_W  = (const float*)d_in[3];
    const float* conv1_b  = (const float*)d_in[4];
    const float* conv2_W  = (const float*)d_in[5];
    const float* conv2_b  = (const float*)d_in[6];
    const float* conv3_W  = (const float*)d_in[7];
    const float* conv3_b  = (const float*)d_in[8];
    const float* p1_relW  = (const float*)d_in[9];
    const float* p1_relb  = (const float*)d_in[10];
    const float* p1_rootW = (const float*)d_in[11];
    const float* p2_relW  = (const float*)d_in[12];
    const float* p2_relb  = (const float*)d_in[13];
    const float* p2_rootW = (const float*)d_in[14];
    const float* fc1_W    = (const float*)d_in[15];
    const float* fc1_b    = (const float*)d_in[16];
    const float* fc2_W    = (const float*)d_in[17];
    const float* fc2_b    = (const float*)d_in[18];
    const float* fc3_W    = (const float*)d_in[19];
    const float* fc3_b    = (const float*)d_in[20];
    float* out = (float*)d_out;

    const int E = in_sizes[1] / 2;
    const int EPG = E / NG;
    const int* e_src = ei;
    const int* e_dst = ei + E;

    // workspace layout
    char* base = (char*)d_ws;
    size_t off = 0;
    auto alloc = [&](size_t bytes) { size_t o = off; off = (off + bytes + 255) & ~(size_t)255; return o; };
    float* hW     = (float*)(base + alloc((size_t)NN * HDIM * 4));   // also xa (NN x FIN)
    float* hcur   = (float*)(base + alloc((size_t)NN * HDIM * 4));
    float* dis    = (float*)(base + alloc(NN * 4));
    float* r_rel  = (float*)(base + alloc(NN * 4));
    float* r_root = (float*)(base + alloc(NN * 4));
    float* score  = (float*)(base + alloc(NN * 4));
    float* nmask  = (float*)(base + alloc(NN * 4));
    int*   rowptr = (int*)(base + alloc((NN + 1) * 4));
    int*   csr    = (int*)(base + alloc((size_t)E * 4));
    float* wedge  = (float*)(base + alloc((size_t)E * 4));
    float* z      = (float*)(base + alloc((size_t)NG * 768 * 4));
    int*   list1  = (int*)(base + alloc((size_t)NG * 128 * 4));
    int*   list2  = (int*)(base + alloc((size_t)NG * 64 * 4));
    int*   list3  = (int*)(base + alloc((size_t)NG * 32 * 4));

    hipMemsetAsync(z, 0, (size_t)NG * 768 * 4, stream);

    // CSR build (canonical sorted-by-src order => deterministic)
    k_csr<<<NG, 256, 0, stream>>>(e_src, e_dst, EPG, rowptr, csr);
    k_sortw<<<NN * 64 / 256, 256, 0, stream>>>(rowptr, csr);

    const int nodeBlocks = NN / 256;
    float* xa = hW;

    // ---- stage 1 ----
    k_dis1<<<nodeBlocks, 256, 0, stream>>>(rowptr, dis);
    k_wedge<<<nodeBlocks, 256, 0, stream>>>(dis, rowptr, csr, wedge);
    k_aggx<<<NN / 8, 256, 0, stream>>>(x, dis, rowptr, csr, wedge, xa);
    {
        dim3 ggrid(HDIM / BN, NN / BM);
        k_sgemm<<<ggrid, 256, 0, stream>>>(xa, conv1_W, hcur, FIN, nullptr, conv1_b);
    }
    k_dots<<<NN * 64 / 256, 256, 0, stream>>>(hcur, p1_relW, p1_rootW, r_rel, r_root);
    k_score<<<nodeBlocks, 256, 0, stream>>>(dis, rowptr, csr, r_rel, r_root, p1_relb, score);
    k_topk<<<NG, 256, 0, stream>>>(score, 128, nmask, list1);
    k_poolout2<<<NG * 4, 256, 0, stream>>>(hcur, score, list1, 128, 1.0f / 128.0f, z);

    // ---- stages 2 & 3 ----
    struct Stage {
        const float* W; const float* b;
        const float* wrel; const float* brel; const float* wroot;
        int kpool;
        const int* list; int nact;
        int* outlist;
    };
    Stage stages[2] = {
        { conv2_W, conv2_b, p2_relW, p2_relb, p2_rootW, 64, list1, 16384, list2 },
        { conv3_W, conv3_b, p2_relW, p2_relb, p2_rootW, 32, list2, 8192,  list3 },
    };

    for (int t = 0; t < 2; t++) {
        Stage& st = stages[t];
        dim3 ggrid(HDIM / BN, st.nact / BM);
        k_sgemm<<<ggrid, 256, 0, stream>>>(hcur, st.W, hW, HDIM, st.list, nullptr);
        k_dis<<<nodeBlocks, 256, 0, stream>>>(nmask, rowptr, csr, dis);
        k_wedge<<<nodeBlocks, 256, 0, stream>>>(dis, rowptr, csr, wedge);
        int bpg = st.nact / (NG * 4);
        k_gcn_agg<<<st.nact / 4, 256, 0, stream>>>(hW, dis, rowptr, csr, wedge, st.b,
                                                   st.list, bpg, st.wrel, st.wroot,
                                                   hcur, r_rel, r_root);
        k_score<<<nodeBlocks, 256, 0, stream>>>(dis, rowptr, csr, r_rel, r_root, st.brel, score);
        k_topk<<<NG, 256, 0, stream>>>(score, st.kpool, nmask, st.outlist);
        k_poolout2<<<NG * 4, 256, 0, stream>>>(hcur, score, st.outlist, st.kpool,
                                               1.0f / (float)st.kpool, z);
    }

    k_mlp<<<NG, 256, 0, stream>>>(z, fc1_W, fc1_b, fc2_W, fc2_b, fc3_W, fc3_b, out);
}

// Round 7
// 355.151 us; speedup vs baseline: 1.7304x; 1.0154x over previous
//
#include <hip/hip_runtime.h>
#include <math.h>

#define NG 128          // graphs
#define NPG 256         // nodes per graph
#define NN 32768        // total nodes
#define HDIM 256        // hidden
#define FIN 128         // input features

// ---------------- CSR build: block per graph, LDS counting sort ----------------
__global__ __launch_bounds__(256) void k_csr(const int* __restrict__ esrc,
                                             const int* __restrict__ edst, int EPG,
                                             int* __restrict__ rowptr, int* __restrict__ csr) {
    __shared__ int cnt[NPG];
    __shared__ int pref[NPG];
    __shared__ int cur[NPG];
    int g = blockIdx.x, tid = threadIdx.x;
    cnt[tid] = 0;
    __syncthreads();
    int base = g * EPG;
    for (int e = base + tid; e < base + EPG; e += 256)
        atomicAdd(&cnt[edst[e] & (NPG - 1)], 1);
    __syncthreads();
    int v = cnt[tid];
    pref[tid] = v;
    __syncthreads();
    for (int off = 1; off < NPG; off <<= 1) {
        int t = (tid >= off) ? pref[tid - off] : 0;
        __syncthreads();
        pref[tid] += t;
        __syncthreads();
    }
    int excl = pref[tid] - v;
    rowptr[g * NPG + tid] = base + excl;
    cur[tid] = base + excl;
    if (g == 0 && tid == 0) rowptr[NN] = NG * EPG;
    __syncthreads();
    for (int e = base + tid; e < base + EPG; e += 256) {
        int d = edst[e] & (NPG - 1);
        int p = atomicAdd(&cur[d], 1);
        csr[p] = esrc[e];
    }
}

// canonical order: wave-parallel rank sort of each node's segment by src value
__global__ __launch_bounds__(256) void k_sortw(const int* __restrict__ rowptr, int* __restrict__ csr) {
    int wid = (blockIdx.x * blockDim.x + threadIdx.x) >> 6;
    int lane = threadIdx.x & 63;
    if (wid >= NN) return;
    int e0 = rowptr[wid];
    int d = rowptr[wid + 1] - e0;
    if (d <= 1) return;
    if (d <= 64) {
        int key = (lane < d) ? csr[e0 + lane] : 0x7fffffff;
        int rank = 0;
        for (int j = 0; j < d; j++) {
            int kj = __shfl(key, j);
            rank += (kj < key || (kj == key && j < lane)) ? 1 : 0;
        }
        if (lane < d) csr[e0 + rank] = key;
    } else if (lane == 0) {
        for (int a = e0 + 1; a < e0 + d; a++) {
            int key = csr[a];
            int b = a - 1;
            while (b >= e0 && csr[b] > key) { csr[b + 1] = csr[b]; b--; }
            csr[b + 1] = key;
        }
    }
}

// ---------------- SGEMM: C[list[m] x 256] = A[list[m] x K] @ B[K x 256], f32 ----------------
#define BM 64
#define BN 64
#define BK 16
__global__ __launch_bounds__(256) void k_sgemm(const float* __restrict__ A,
                                               const float* __restrict__ B,
                                               float* __restrict__ C, int K,
                                               const int* __restrict__ list,
                                               const float* __restrict__ brelu) {
    const int N = HDIM;
    __shared__ float As[BK][BM];
    __shared__ float Bs[BK][BN];
    int tid = threadIdx.x;
    int tx = tid & 15, ty = tid >> 4;
    int row0 = blockIdx.y * BM, col0 = blockIdx.x * BN;
    int lm = tid >> 2;
    int arow = list ? list[row0 + lm] : (row0 + lm);
    int crow[4];
#pragma unroll
    for (int i = 0; i < 4; i++) {
        int r = row0 + ty * 4 + i;
        crow[i] = list ? list[r] : r;
    }
    float acc[4][4] = {};
    for (int kb = 0; kb < K; kb += BK) {
        {
            int k = (tid & 3) * 4;
            float4 av = *reinterpret_cast<const float4*>(&A[(size_t)arow * K + kb + k]);
            As[k + 0][lm] = av.x; As[k + 1][lm] = av.y; As[k + 2][lm] = av.z; As[k + 3][lm] = av.w;
        }
        {
            int l = tid * 4;
            int k = l >> 6, c = l & 63;
            *reinterpret_cast<float4*>(&Bs[k][c]) =
                *reinterpret_cast<const float4*>(&B[(size_t)(kb + k) * N + col0 + c]);
        }
        __syncthreads();
#pragma unroll
        for (int k = 0; k < BK; k++) {
            float4 a = *reinterpret_cast<float4*>(&As[k][ty * 4]);
            float4 b = *reinterpret_cast<float4*>(&Bs[k][tx * 4]);
            float av[4] = {a.x, a.y, a.z, a.w};
            float bv[4] = {b.x, b.y, b.z, b.w};
#pragma unroll
            for (int i = 0; i < 4; i++)
#pragma unroll
                for (int j = 0; j < 4; j++) acc[i][j] += av[i] * bv[j];
        }
        __syncthreads();
    }
    float4 bb = make_float4(0.f, 0.f, 0.f, 0.f);
    if (brelu) bb = *reinterpret_cast<const float4*>(&brelu[col0 + tx * 4]);
#pragma unroll
    for (int i = 0; i < 4; i++) {
        float4 v = make_float4(acc[i][0], acc[i][1], acc[i][2], acc[i][3]);
        if (brelu) {
            v.x = fmaxf(v.x + bb.x, 0.f);
            v.y = fmaxf(v.y + bb.y, 0.f);
            v.z = fmaxf(v.z + bb.z, 0.f);
            v.w = fmaxf(v.w + bb.w, 0.f);
        }
        *reinterpret_cast<float4*>(&C[(size_t)crow[i] * N + col0 + tx * 4]) = v;
    }
}

// ---------------- per-stage kernels ----------------
__global__ void k_dis1(const int* __restrict__ rowptr, float* __restrict__ dis) {
    int i = blockIdx.x * blockDim.x + threadIdx.x;
    if (i < NN) dis[i] = rsqrtf((float)(1 + rowptr[i + 1] - rowptr[i]));
}

__global__ void k_dis(const float* __restrict__ nmask, const int* __restrict__ rowptr,
                      const int* __restrict__ csr, float* __restrict__ dis) {
    int i = blockIdx.x * blockDim.x + threadIdx.x;
    if (i >= NN) return;
    if (nmask[i] <= 0.f) { dis[i] = 0.f; return; }
    int e0 = rowptr[i], e1 = rowptr[i + 1];
    int cnt = 1;
    for (int e = e0; e < e1; e++) cnt += (nmask[csr[e]] > 0.f) ? 1 : 0;
    dis[i] = rsqrtf((float)cnt);
}

__global__ void k_wedge(const float* __restrict__ dis, const int* __restrict__ rowptr,
                        const int* __restrict__ csr, float* __restrict__ w) {
    int i = blockIdx.x * blockDim.x + threadIdx.x;
    if (i >= NN) return;
    float di = dis[i];
    if (di <= 0.f) return;
    int e0 = rowptr[i], e1 = rowptr[i + 1];
    for (int e = e0; e < e1; e++) w[e] = dis[csr[e]] * di;
}

// XCD-locality swizzle
__device__ __forceinline__ int swz_block(int bid, int bpg) {
    int xcd = bid & 7, r = bid >> 3;
    int graph = xcd * (NG / 8) + r / bpg;
    int sub = r - (r / bpg) * bpg;
    return graph * bpg + sub;
}

// stage 1: xa = D^{-1/2}(A+I)D^{-1/2} x ; half-wave (32 lanes x float4) per node
__global__ __launch_bounds__(256) void k_aggx(const float* __restrict__ x,
                                              const float* __restrict__ dis,
                                              const int* __restrict__ rowptr,
                                              const int* __restrict__ csr,
                                              const float* __restrict__ wedge,
                                              float* __restrict__ xa) {
    int blk = swz_block(blockIdx.x, NPG / 8);
    int n = blk * 8 + (threadIdx.x >> 5);
    int lane = threadIdx.x & 31;
    const float4* xp = reinterpret_cast<const float4*>(x);
    float di = dis[n];
    float4 h = xp[(size_t)n * (FIN / 4) + lane];
    float self = di * di;
    float ax = h.x * self, ay = h.y * self, az = h.z * self, aw = h.w * self;
    int e0 = rowptr[n], e1 = rowptr[n + 1];
    for (int e = e0; e < e1; e++) {
        int s = csr[e];
        float w = wedge[e];
        float4 hs = xp[(size_t)s * (FIN / 4) + lane];
        ax += hs.x * w; ay += hs.y * w; az += hs.z * w; aw += hs.w * w;
    }
    float4 o = make_float4(ax, ay, az, aw);
    reinterpret_cast<float4*>(xa)[(size_t)n * (FIN / 4) + lane] = o;
}

// wave per node: r_rel = h . w_rel, r_root = h . w_root (stage 1)
__global__ __launch_bounds__(256) void k_dots(const float* __restrict__ h,
                                              const float* __restrict__ w_rel,
                                              const float* __restrict__ w_root,
                                              float* __restrict__ r_rel,
                                              float* __restrict__ r_root) {
    int wid = (blockIdx.x * blockDim.x + threadIdx.x) >> 6;
    int lane = threadIdx.x & 63;
    if (wid >= NN) return;
    float4 hv = *reinterpret_cast<const float4*>(&h[(size_t)wid * HDIM + lane * 4]);
    float4 wr = *reinterpret_cast<const float4*>(&w_rel[lane * 4]);
    float4 wo = *reinterpret_cast<const float4*>(&w_root[lane * 4]);
    float s1 = hv.x * wr.x + hv.y * wr.y + hv.z * wr.z + hv.w * wr.w;
    float s2 = hv.x * wo.x + hv.y * wo.y + hv.z * wo.z + hv.w * wo.w;
    for (int off = 32; off > 0; off >>= 1) {
        s1 += __shfl_down(s1, off);
        s2 += __shfl_down(s2, off);
    }
    if (lane == 0) { r_rel[wid] = s1; r_root[wid] = s2; }
}

// stages 2/3: wave per ACTIVE node, gather on hW, fused bias+relu+score dots
__global__ __launch_bounds__(256) void k_gcn_agg(const float* __restrict__ hW,
                                                 const float* __restrict__ dis,
                                                 const int* __restrict__ rowptr,
                                                 const int* __restrict__ csr,
                                                 const float* __restrict__ wedge,
                                                 const float* __restrict__ bias,
                                                 const int* __restrict__ list, int bpg,
                                                 const float* __restrict__ w_rel,
                                                 const float* __restrict__ w_root,
                                                 float* __restrict__ out,
                                                 float* __restrict__ r_rel,
                                                 float* __restrict__ r_root) {
    int blk = swz_block(blockIdx.x, bpg);
    int idx = blk * 4 + (threadIdx.x >> 6);
    int lane = threadIdx.x & 63;
    int wid = list[idx];
    float di = dis[wid];
    float4 h = *reinterpret_cast<const float4*>(&hW[(size_t)wid * HDIM + lane * 4]);
    float self = di * di;
    float ax = h.x * self, ay = h.y * self, az = h.z * self, aw = h.w * self;
    int e0 = rowptr[wid], e1 = rowptr[wid + 1];
    for (int e = e0; e < e1; e++) {
        float w = wedge[e];
        if (w > 0.f) {
            int s = csr[e];
            float4 hs = *reinterpret_cast<const float4*>(&hW[(size_t)s * HDIM + lane * 4]);
            ax += hs.x * w; ay += hs.y * w; az += hs.z * w; aw += hs.w * w;
        }
    }
    float4 b = *reinterpret_cast<const float4*>(&bias[lane * 4]);
    float4 o;
    o.x = fmaxf(ax + b.x, 0.f);
    o.y = fmaxf(ay + b.y, 0.f);
    o.z = fmaxf(az + b.z, 0.f);
    o.w = fmaxf(aw + b.w, 0.f);
    *reinterpret_cast<float4*>(&out[(size_t)wid * HDIM + lane * 4]) = o;
    float4 wr = *reinterpret_cast<const float4*>(&w_rel[lane * 4]);
    float4 wo = *reinterpret_cast<const float4*>(&w_root[lane * 4]);
    float s1 = o.x * wr.x + o.y * wr.y + o.z * wr.z + o.w * wr.w;
    float s2 = o.x * wo.x + o.y * wo.y + o.z * wo.z + o.w * wo.w;
    for (int off = 32; off > 0; off >>= 1) {
        s1 += __shfl_down(s1, off);
        s2 += __shfl_down(s2, off);
    }
    if (lane == 0) { r_rel[wid] = s1; r_root[wid] = s2; }
}

// fused score + stable top-k, block per graph.
// score_i = b_rel + r_root_i + sum_{j in N(i), active} r_rel_j  (inactive slots zero-filled:
// adding +0.0f is bit-exact vs skipping). Writes nmask, list, tansel.
__global__ __launch_bounds__(256) void k_topkf(const float* __restrict__ dis,
                                               const int* __restrict__ rowptr,
                                               const int* __restrict__ csr,
                                               const float* __restrict__ r_rel,
                                               const float* __restrict__ r_root,
                                               const float* __restrict__ b_rel, int k,
                                               float* __restrict__ nmask,
                                               int* __restrict__ list,
                                               float* __restrict__ tansel) {
    __shared__ float rrel[NPG];
    __shared__ float sc[NPG];
    __shared__ int pref[NPG];
    int g = blockIdx.x, tid = threadIdx.x;
    int n = g * NPG + tid;
    bool act = dis[n] > 0.f;
    rrel[tid] = act ? r_rel[n] : 0.f;
    __syncthreads();
    float my;
    if (act) {
        float s = b_rel[0] + r_root[n];
        int e0 = rowptr[n], e1 = rowptr[n + 1];
        for (int e = e0; e < e1; e++) s += rrel[csr[e] & (NPG - 1)];
        my = s;
    } else {
        my = -INFINITY;
    }
    sc[tid] = my;
    __syncthreads();
    int cnt = 0;
    for (int j = 0; j < NPG; j++) {
        float v = sc[j];
        cnt += (v > my || (v == my && j < tid)) ? 1 : 0;
    }
    int a = (cnt < k) ? 1 : 0;
    nmask[n] = (float)a;
    pref[tid] = a;
    __syncthreads();
    for (int off = 1; off < NPG; off <<= 1) {
        int v = (tid >= off) ? pref[tid - off] : 0;
        __syncthreads();
        pref[tid] += v;
        __syncthreads();
    }
    if (a) {
        int rk = pref[tid] - 1;
        list[g * k + rk] = n;
        tansel[g * k + rk] = tanhf(my);
    }
}

// grid = NG*4: block = (graph, 64-feature chunk); 256 thr = 64 feat x 4 node-partitions
__global__ __launch_bounds__(256) void k_poolout2(float* __restrict__ h,
                                                  const float* __restrict__ tansel,
                                                  const int* __restrict__ list, int k,
                                                  float invk, float* __restrict__ z) {
    __shared__ float tv[128];        // k <= 128
    __shared__ float red_s[4][64];
    __shared__ float red_m[4][64];
    int g = blockIdx.x >> 2, fc = blockIdx.x & 3;
    int tid = threadIdx.x;
    int x = tid & 63, y = tid >> 6;
    if (tid < k) tv[tid] = tansel[g * k + tid];
    __syncthreads();
    int f = fc * 64 + x;
    float s = 0.f, mx = -INFINITY;
    for (int idx = y; idx < k; idx += 4) {
        int node = list[g * k + idx];
        size_t p = (size_t)node * HDIM + f;
        float v = h[p] * tv[idx];
        h[p] = v;
        s += v;
        mx = fmaxf(mx, v);
    }
    red_s[y][x] = s;
    red_m[y][x] = mx;
    __syncthreads();
    if (y == 0) {
        s = red_s[0][x] + red_s[1][x] + red_s[2][x] + red_s[3][x];
        mx = fmaxf(fmaxf(red_m[0][x], red_m[1][x]), fmaxf(red_m[2][x], red_m[3][x]));
        z[g * 768 + f] += s * invk;
        z[g * 768 + 256 + f] += mx;
        z[g * 768 + 512 + f] += s;
    }
}

// ---------------- MLP: fc1 (NG*4 blocks), then fc2+fc3+log_softmax (NG blocks) ----------------
// fc1: t1[g,256] = relu(z[g,768] @ W1 + b1); block = (g, 64-output chunk), 4-way k-split
__global__ __launch_bounds__(256) void k_fc1(const float* __restrict__ z,
                                             const float* __restrict__ W1,
                                             const float* __restrict__ b1,
                                             float* __restrict__ t1) {
    __shared__ float zb[768];
    __shared__ float red[4][64];
    int g = blockIdx.x >> 2, oc = blockIdx.x & 3;
    int tid = threadIdx.x;
    zb[tid] = z[g * 768 + tid];
    zb[tid + 256] = z[g * 768 + 256 + tid];
    zb[tid + 512] = z[g * 768 + 512 + tid];
    __syncthreads();
    int x = tid & 63, y = tid >> 6;
    int col = oc * 64 + x;
    float s = 0.f;
    for (int i = y * 192; i < (y + 1) * 192; i++) s += zb[i] * W1[(size_t)i * 256 + col];
    red[y][x] = s;
    __syncthreads();
    if (y == 0) {
        float t = red[0][x] + red[1][x] + red[2][x] + red[3][x] + b1[col];
        t1[g * 256 + col] = fmaxf(t, 0.f);
    }
}

__global__ __launch_bounds__(256) void k_mlp2(const float* __restrict__ t1,
                                              const float* __restrict__ W2, const float* __restrict__ b2,
                                              const float* __restrict__ W3, const float* __restrict__ b3,
                                              float* __restrict__ out) {
    __shared__ float t1s[256];
    __shared__ float red[2][128];
    __shared__ float t2s[128];
    __shared__ float t3[10];
    __shared__ float lse;
    int g = blockIdx.x, tid = threadIdx.x;
    t1s[tid] = t1[g * 256 + tid];
    __syncthreads();
    int x = tid & 127, y = tid >> 7;
    float s = 0.f;
    for (int i = y * 128; i < (y + 1) * 128; i++) s += t1s[i] * W2[(size_t)i * 128 + x];
    red[y][x] = s;
    __syncthreads();
    if (y == 0) t2s[x] = fmaxf(red[0][x] + red[1][x] + b2[x], 0.f);
    __syncthreads();
    if (tid < 10) {
        float v = b3[tid];
        for (int i = 0; i < 128; i++) v += t2s[i] * W3[(size_t)i * 10 + tid];
        t3[tid] = v;
    }
    __syncthreads();
    if (tid == 0) {
        float m = t3[0];
        for (int c = 1; c < 10; c++) m = fmaxf(m, t3[c]);
        float se = 0.f;
        for (int c = 0; c < 10; c++) se += expf(t3[c] - m);
        lse = m + logf(se);
    }
    __syncthreads();
    if (tid < 10) out[g * 10 + tid] = t3[tid] - lse;
}

// ---------------- launcher ----------------
extern "C" void kernel_launch(void* const* d_in, const int* in_sizes, int n_in,
                              void* d_out, int out_size, void* d_ws, size_t ws_size,
                              hipStream_t stream) {
    const float* x        = (const float*)d_in[0];
    const int*   ei       = (const int*)d_in[1];
    const float* conv1_W  = (const float*)d_in[3];
    const float* conv1_b  = (const float*)d_in[4];
    const float* conv2_W  = (const float*)d_in[5];
    const float* conv2_b  = (const float*)d_in[6];
    const float* conv3_W  = (const float*)d_in[7];
    const float* conv3_b  = (const float*)d_in[8];
    const float* p1_relW  = (const float*)d_in[9];
    const float* p1_relb  = (const float*)d_in[10];
    const float* p1_rootW = (const float*)d_in[11];
    const float* p2_relW  = (const float*)d_in[12];
    const float* p2_relb  = (const float*)d_in[13];
    const float* p2_rootW = (const float*)d_in[14];
    const float* fc1_W    = (const float*)d_in[15];
    const float* fc1_b    = (const float*)d_in[16];
    const float* fc2_W    = (const float*)d_in[17];
    const float* fc2_b    = (const float*)d_in[18];
    const float* fc3_W    = (const float*)d_in[19];
    const float* fc3_b    = (const float*)d_in[20];
    float* out = (float*)d_out;

    const int E = in_sizes[1] / 2;
    const int EPG = E / NG;
    const int* e_src = ei;
    const int* e_dst = ei + E;

    // workspace layout
    char* base = (char*)d_ws;
    size_t off = 0;
    auto alloc = [&](size_t bytes) { size_t o = off; off = (off + bytes + 255) & ~(size_t)255; return o; };
    float* hW     = (float*)(base + alloc((size_t)NN * HDIM * 4));   // also xa (NN x FIN)
    float* hcur   = (float*)(base + alloc((size_t)NN * HDIM * 4));
    float* dis    = (float*)(base + alloc(NN * 4));
    float* r_rel  = (float*)(base + alloc(NN * 4));
    float* r_root = (float*)(base + alloc(NN * 4));
    float* nmask  = (float*)(base + alloc(NN * 4));
    int*   rowptr = (int*)(base + alloc((NN + 1) * 4));
    int*   csr    = (int*)(base + alloc((size_t)E * 4));
    float* wedge  = (float*)(base + alloc((size_t)E * 4));
    float* z      = (float*)(base + alloc((size_t)NG * 768 * 4));
    float* t1buf  = (float*)(base + alloc((size_t)NG * 256 * 4));
    int*   list1  = (int*)(base + alloc((size_t)NG * 128 * 4));
    int*   list2  = (int*)(base + alloc((size_t)NG * 64 * 4));
    int*   list3  = (int*)(base + alloc((size_t)NG * 32 * 4));
    float* tans1  = (float*)(base + alloc((size_t)NG * 128 * 4));
    float* tans2  = (float*)(base + alloc((size_t)NG * 64 * 4));
    float* tans3  = (float*)(base + alloc((size_t)NG * 32 * 4));

    hipMemsetAsync(z, 0, (size_t)NG * 768 * 4, stream);

    // CSR build (canonical sorted-by-src order => deterministic)
    k_csr<<<NG, 256, 0, stream>>>(e_src, e_dst, EPG, rowptr, csr);
    k_sortw<<<NN * 64 / 256, 256, 0, stream>>>(rowptr, csr);

    const int nodeBlocks = NN / 256;
    float* xa = hW;

    // ---- stage 1 ----
    k_dis1<<<nodeBlocks, 256, 0, stream>>>(rowptr, dis);
    k_wedge<<<nodeBlocks, 256, 0, stream>>>(dis, rowptr, csr, wedge);
    k_aggx<<<NN / 8, 256, 0, stream>>>(x, dis, rowptr, csr, wedge, xa);
    {
        dim3 ggrid(HDIM / BN, NN / BM);
        k_sgemm<<<ggrid, 256, 0, stream>>>(xa, conv1_W, hcur, FIN, nullptr, conv1_b);
    }
    k_dots<<<NN * 64 / 256, 256, 0, stream>>>(hcur, p1_relW, p1_rootW, r_rel, r_root);
    k_topkf<<<NG, 256, 0, stream>>>(dis, rowptr, csr, r_rel, r_root, p1_relb, 128,
                                    nmask, list1, tans1);
    k_poolout2<<<NG * 4, 256, 0, stream>>>(hcur, tans1, list1, 128, 1.0f / 128.0f, z);

    // ---- stages 2 & 3 ----
    struct Stage {
        const float* W; const float* b;
        const float* wrel; const float* brel; const float* wroot;
        int kpool;
        const int* list; int nact;
        int* outlist; float* outtans;
    };
    Stage stages[2] = {
        { conv2_W, conv2_b, p2_relW, p2_relb, p2_rootW, 64, list1, 16384, list2, tans2 },
        { conv3_W, conv3_b, p2_relW, p2_relb, p2_rootW, 32, list2, 8192,  list3, tans3 },
    };

    for (int t = 0; t < 2; t++) {
        Stage& st = stages[t];
        dim3 ggrid(HDIM / BN, st.nact / BM);
        k_sgemm<<<ggrid, 256, 0, stream>>>(hcur, st.W, hW, HDIM, st.list, nullptr);
        k_dis<<<nodeBlocks, 256, 0, stream>>>(nmask, rowptr, csr, dis);
        k_wedge<<<nodeBlocks, 256, 0, stream>>>(dis, rowptr, csr, wedge);
        int bpg = st.nact / (NG * 4);
        k_gcn_agg<<<st.nact / 4, 256, 0, stream>>>(hW, dis, rowptr, csr, wedge, st.b,
                                                   st.list, bpg, st.wrel, st.wroot,
                                                   hcur, r_rel, r_root);
        k_topkf<<<NG, 256, 0, stream>>>(dis, rowptr, csr, r_rel, r_root, st.brel, st.kpool,
                                        nmask, st.outlist, st.outtans);
        k_poolout2<<<NG * 4, 256, 0, stream>>>(hcur, st.outtans, st.outlist, st.kpool,
                                               1.0f / (float)st.kpool, z);
    }

    k_fc1<<<NG * 4, 256, 0, stream>>>(z, fc1_W, fc1_b, t1buf);
    k_mlp2<<<NG, 256, 0, stream>>>(t1buf, fc2_W, fc2_b, fc3_W, fc3_b, out);
}

// Round 8
// 307.968 us; speedup vs baseline: 1.9955x; 1.1532x over previous
//
#include <hip/hip_runtime.h>
#include <math.h>

#define NG 128          // graphs
#define NPG 256         // nodes per graph
#define NN 32768        // total nodes
#define HDIM 256        // hidden
#define FIN 128         // input features

// ---------------- CSR build: block per graph, LDS counting sort ----------------
__global__ __launch_bounds__(256) void k_csr(const int* __restrict__ esrc,
                                             const int* __restrict__ edst, int EPG,
                                             int* __restrict__ rowptr, int* __restrict__ csr) {
    __shared__ int cnt[NPG];
    __shared__ int pref[NPG];
    __shared__ int cur[NPG];
    int g = blockIdx.x, tid = threadIdx.x;
    cnt[tid] = 0;
    __syncthreads();
    int base = g * EPG;
    for (int e = base + tid; e < base + EPG; e += 256)
        atomicAdd(&cnt[edst[e] & (NPG - 1)], 1);
    __syncthreads();
    int v = cnt[tid];
    pref[tid] = v;
    __syncthreads();
    for (int off = 1; off < NPG; off <<= 1) {
        int t = (tid >= off) ? pref[tid - off] : 0;
        __syncthreads();
        pref[tid] += t;
        __syncthreads();
    }
    int excl = pref[tid] - v;
    rowptr[g * NPG + tid] = base + excl;
    cur[tid] = base + excl;
    if (g == 0 && tid == 0) rowptr[NN] = NG * EPG;
    __syncthreads();
    for (int e = base + tid; e < base + EPG; e += 256) {
        int d = edst[e] & (NPG - 1);
        int p = atomicAdd(&cur[d], 1);
        csr[p] = esrc[e];
    }
}

// canonical sort by src value + stage-1 edge weights (all nodes active):
// wedge[e] = rsqrt(1+deg(src)) * rsqrt(1+deg(dst))
__global__ __launch_bounds__(256) void k_sortw(const int* __restrict__ rowptr,
                                               int* __restrict__ csr,
                                               float* __restrict__ wedge) {
    int wid = (blockIdx.x * blockDim.x + threadIdx.x) >> 6;
    int lane = threadIdx.x & 63;
    if (wid >= NN) return;
    int e0 = rowptr[wid];
    int d = rowptr[wid + 1] - e0;
    if (d == 0) return;
    float ddst = rsqrtf((float)(1 + d));
    if (d <= 64) {
        int key = (lane < d) ? csr[e0 + lane] : 0x7fffffff;
        int rank = 0;
        for (int j = 0; j < d; j++) {
            int kj = __shfl(key, j);
            rank += (kj < key || (kj == key && j < lane)) ? 1 : 0;
        }
        if (lane < d) {
            csr[e0 + rank] = key;
            int sdeg = rowptr[key + 1] - rowptr[key];
            wedge[e0 + rank] = rsqrtf((float)(1 + sdeg)) * ddst;
        }
    } else if (lane == 0) {
        for (int a = e0 + 1; a < e0 + d; a++) {
            int key = csr[a];
            int b = a - 1;
            while (b >= e0 && csr[b] > key) { csr[b + 1] = csr[b]; b--; }
            csr[b + 1] = key;
        }
        for (int a = e0; a < e0 + d; a++) {
            int s = csr[a];
            wedge[a] = rsqrtf((float)(1 + rowptr[s + 1] - rowptr[s])) * ddst;
        }
    }
}

// ---------------- SGEMM: C[list[m] x 256] = A[list[m] x K] @ B[K x 256], f32 ----------------
// optional epilogues: bias+relu (brelu); per-col-block score dots (wrel/wroot -> rrel4/rroot4)
#define BM 64
#define BN 64
#define BK 16
__global__ __launch_bounds__(256) void k_sgemm(const float* __restrict__ A,
                                               const float* __restrict__ B,
                                               float* __restrict__ C, int K,
                                               const int* __restrict__ list,
                                               const float* __restrict__ brelu,
                                               const float* __restrict__ wrel,
                                               const float* __restrict__ wroot,
                                               float* __restrict__ rrel4,
                                               float* __restrict__ rroot4) {
    const int N = HDIM;
    __shared__ float As[BK][BM];
    __shared__ float Bs[BK][BN];
    int tid = threadIdx.x;
    int tx = tid & 15, ty = tid >> 4;
    int row0 = blockIdx.y * BM, col0 = blockIdx.x * BN;
    int lm = tid >> 2;
    int arow = list ? list[row0 + lm] : (row0 + lm);
    int crow[4];
#pragma unroll
    for (int i = 0; i < 4; i++) {
        int r = row0 + ty * 4 + i;
        crow[i] = list ? list[r] : r;
    }
    float acc[4][4] = {};
    for (int kb = 0; kb < K; kb += BK) {
        {
            int k = (tid & 3) * 4;
            float4 av = *reinterpret_cast<const float4*>(&A[(size_t)arow * K + kb + k]);
            As[k + 0][lm] = av.x; As[k + 1][lm] = av.y; As[k + 2][lm] = av.z; As[k + 3][lm] = av.w;
        }
        {
            int l = tid * 4;
            int k = l >> 6, c = l & 63;
            *reinterpret_cast<float4*>(&Bs[k][c]) =
                *reinterpret_cast<const float4*>(&B[(size_t)(kb + k) * N + col0 + c]);
        }
        __syncthreads();
#pragma unroll
        for (int k = 0; k < BK; k++) {
            float4 a = *reinterpret_cast<float4*>(&As[k][ty * 4]);
            float4 b = *reinterpret_cast<float4*>(&Bs[k][tx * 4]);
            float av[4] = {a.x, a.y, a.z, a.w};
            float bv[4] = {b.x, b.y, b.z, b.w};
#pragma unroll
            for (int i = 0; i < 4; i++)
#pragma unroll
                for (int j = 0; j < 4; j++) acc[i][j] += av[i] * bv[j];
        }
        __syncthreads();
    }
    float4 bb = make_float4(0.f, 0.f, 0.f, 0.f);
    if (brelu) bb = *reinterpret_cast<const float4*>(&brelu[col0 + tx * 4]);
    float4 wr = make_float4(0.f, 0.f, 0.f, 0.f), wo = wr;
    if (wrel) {
        wr = *reinterpret_cast<const float4*>(&wrel[col0 + tx * 4]);
        wo = *reinterpret_cast<const float4*>(&wroot[col0 + tx * 4]);
    }
#pragma unroll
    for (int i = 0; i < 4; i++) {
        float4 v = make_float4(acc[i][0], acc[i][1], acc[i][2], acc[i][3]);
        if (brelu) {
            v.x = fmaxf(v.x + bb.x, 0.f);
            v.y = fmaxf(v.y + bb.y, 0.f);
            v.z = fmaxf(v.z + bb.z, 0.f);
            v.w = fmaxf(v.w + bb.w, 0.f);
        }
        *reinterpret_cast<float4*>(&C[(size_t)crow[i] * N + col0 + tx * 4]) = v;
        if (wrel) {
            float s1 = v.x * wr.x + v.y * wr.y + v.z * wr.z + v.w * wr.w;
            float s2 = v.x * wo.x + v.y * wo.y + v.z * wo.z + v.w * wo.w;
            for (int off = 8; off > 0; off >>= 1) {
                s1 += __shfl_down(s1, off, 16);
                s2 += __shfl_down(s2, off, 16);
            }
            if (tx == 0) {
                rrel4[(size_t)crow[i] * 4 + blockIdx.x] = s1;
                rroot4[(size_t)crow[i] * 4 + blockIdx.x] = s2;
            }
        }
    }
}

// ---------------- stage 1 aggregation (dis inline from degrees) ----------------
__device__ __forceinline__ int swz_block(int bid, int bpg) {
    int xcd = bid & 7, r = bid >> 3;
    int graph = xcd * (NG / 8) + r / bpg;
    int sub = r - (r / bpg) * bpg;
    return graph * bpg + sub;
}

__global__ __launch_bounds__(256) void k_aggx(const float* __restrict__ x,
                                              const int* __restrict__ rowptr,
                                              const int* __restrict__ csr,
                                              const float* __restrict__ wedge,
                                              float* __restrict__ xa) {
    int blk = swz_block(blockIdx.x, NPG / 8);
    int n = blk * 8 + (threadIdx.x >> 5);
    int lane = threadIdx.x & 31;
    const float4* xp = reinterpret_cast<const float4*>(x);
    int e0 = rowptr[n], e1 = rowptr[n + 1];
    float di = rsqrtf((float)(1 + e1 - e0));
    float4 h = xp[(size_t)n * (FIN / 4) + lane];
    float self = di * di;
    float ax = h.x * self, ay = h.y * self, az = h.z * self, aw = h.w * self;
    for (int e = e0; e < e1; e++) {
        int s = csr[e];
        float w = wedge[e];
        float4 hs = xp[(size_t)s * (FIN / 4) + lane];
        ax += hs.x * w; ay += hs.y * w; az += hs.z * w; aw += hs.w * w;
    }
    float4 o = make_float4(ax, ay, az, aw);
    reinterpret_cast<float4*>(xa)[(size_t)n * (FIN / 4) + lane] = o;
}

// stages 2/3: wave per ACTIVE node, gather on hW, fused bias+relu+score dots
__global__ __launch_bounds__(256) void k_gcn_agg(const float* __restrict__ hW,
                                                 const float* __restrict__ dis,
                                                 const int* __restrict__ rowptr,
                                                 const int* __restrict__ csr,
                                                 const float* __restrict__ wedge,
                                                 const float* __restrict__ bias,
                                                 const int* __restrict__ list, int bpg,
                                                 const float* __restrict__ w_rel,
                                                 const float* __restrict__ w_root,
                                                 float* __restrict__ out,
                                                 float* __restrict__ r_rel,
                                                 float* __restrict__ r_root) {
    int blk = swz_block(blockIdx.x, bpg);
    int idx = blk * 4 + (threadIdx.x >> 6);
    int lane = threadIdx.x & 63;
    int wid = list[idx];
    float di = dis[wid];
    float4 h = *reinterpret_cast<const float4*>(&hW[(size_t)wid * HDIM + lane * 4]);
    float self = di * di;
    float ax = h.x * self, ay = h.y * self, az = h.z * self, aw = h.w * self;
    int e0 = rowptr[wid], e1 = rowptr[wid + 1];
    for (int e = e0; e < e1; e++) {
        float w = wedge[e];
        if (w > 0.f) {
            int s = csr[e];
            float4 hs = *reinterpret_cast<const float4*>(&hW[(size_t)s * HDIM + lane * 4]);
            ax += hs.x * w; ay += hs.y * w; az += hs.z * w; aw += hs.w * w;
        }
    }
    float4 b = *reinterpret_cast<const float4*>(&bias[lane * 4]);
    float4 o;
    o.x = fmaxf(ax + b.x, 0.f);
    o.y = fmaxf(ay + b.y, 0.f);
    o.z = fmaxf(az + b.z, 0.f);
    o.w = fmaxf(aw + b.w, 0.f);
    *reinterpret_cast<float4*>(&out[(size_t)wid * HDIM + lane * 4]) = o;
    float4 wr = *reinterpret_cast<const float4*>(&w_rel[lane * 4]);
    float4 wo = *reinterpret_cast<const float4*>(&w_root[lane * 4]);
    float s1 = o.x * wr.x + o.y * wr.y + o.z * wr.z + o.w * wr.w;
    float s2 = o.x * wo.x + o.y * wo.y + o.z * wo.z + o.w * wo.w;
    for (int off = 32; off > 0; off >>= 1) {
        s1 += __shfl_down(s1, off);
        s2 += __shfl_down(s2, off);
    }
    if (lane == 0) { r_rel[wid] = s1; r_root[wid] = s2; }
}

// fused score + stable top-k + (optionally) next-stage dis/wedge, block per graph
template<bool STAGE1, bool EMIT>
__global__ __launch_bounds__(256) void k_topkf(const float* __restrict__ dis,
                                               const int* __restrict__ rowptr,
                                               const int* __restrict__ csr,
                                               const float* __restrict__ r_rel,
                                               const float* __restrict__ r_root,
                                               const float* __restrict__ rrel4,
                                               const float* __restrict__ rroot4,
                                               const float* __restrict__ b_rel, int k,
                                               int* __restrict__ list,
                                               float* __restrict__ tansel,
                                               float* __restrict__ disN,
                                               float* __restrict__ wedgeN) {
    __shared__ float rrel[NPG];
    __shared__ float sc[NPG];
    __shared__ int pref[NPG];
    __shared__ int sels[NPG];
    __shared__ float disn[NPG];
    int g = blockIdx.x, tid = threadIdx.x;
    int n = g * NPG + tid;
    bool act = STAGE1 ? true : (dis[n] > 0.f);
    float rr, ro;
    if (STAGE1) {
        rr = ((rrel4[(size_t)n * 4 + 0] + rrel4[(size_t)n * 4 + 1]) +
              rrel4[(size_t)n * 4 + 2]) + rrel4[(size_t)n * 4 + 3];
        ro = ((rroot4[(size_t)n * 4 + 0] + rroot4[(size_t)n * 4 + 1]) +
              rroot4[(size_t)n * 4 + 2]) + rroot4[(size_t)n * 4 + 3];
    } else {
        rr = act ? r_rel[n] : 0.f;
        ro = act ? r_root[n] : 0.f;
    }
    rrel[tid] = act ? rr : 0.f;
    __syncthreads();
    int e0 = rowptr[n], e1 = rowptr[n + 1];
    float my;
    if (act) {
        float s = b_rel[0] + ro;
        for (int e = e0; e < e1; e++) s += rrel[csr[e] & (NPG - 1)];
        my = s;
    } else {
        my = -INFINITY;
    }
    sc[tid] = my;
    __syncthreads();
    int cnt = 0;
    for (int j = 0; j < NPG; j++) {
        float v = sc[j];
        cnt += (v > my || (v == my && j < tid)) ? 1 : 0;
    }
    int a = (cnt < k) ? 1 : 0;
    sels[tid] = a;
    pref[tid] = a;
    __syncthreads();
    for (int off = 1; off < NPG; off <<= 1) {
        int v = (tid >= off) ? pref[tid - off] : 0;
        __syncthreads();
        pref[tid] += v;
        __syncthreads();
    }
    if (a) {
        int rk = pref[tid] - 1;
        list[g * k + rk] = n;
        tansel[g * k + rk] = tanhf(my);
    }
    if (EMIT) {
        int c2 = 1;
        for (int e = e0; e < e1; e++) c2 += sels[csr[e] & (NPG - 1)];
        float dn = a ? rsqrtf((float)c2) : 0.f;
        disn[tid] = dn;
        disN[n] = dn;
        __syncthreads();
        if (a) {
            for (int e = e0; e < e1; e++) wedgeN[e] = disn[csr[e] & (NPG - 1)] * dn;
        }
    }
}

// grid = NG*4: block = (graph, 64-feature chunk); 256 thr = 64 feat x 4 node-partitions
template<bool FIRST>
__global__ __launch_bounds__(256) void k_poolout2(float* __restrict__ h,
                                                  const float* __restrict__ tansel,
                                                  const int* __restrict__ list, int k,
                                                  float invk, float* __restrict__ z) {
    __shared__ float tv[128];        // k <= 128
    __shared__ float red_s[4][64];
    __shared__ float red_m[4][64];
    int g = blockIdx.x >> 2, fc = blockIdx.x & 3;
    int tid = threadIdx.x;
    int x = tid & 63, y = tid >> 6;
    if (tid < k) tv[tid] = tansel[g * k + tid];
    __syncthreads();
    int f = fc * 64 + x;
    float s = 0.f, mx = -INFINITY;
    for (int idx = y; idx < k; idx += 4) {
        int node = list[g * k + idx];
        size_t p = (size_t)node * HDIM + f;
        float v = h[p] * tv[idx];
        h[p] = v;
        s += v;
        mx = fmaxf(mx, v);
    }
    red_s[y][x] = s;
    red_m[y][x] = mx;
    __syncthreads();
    if (y == 0) {
        s = red_s[0][x] + red_s[1][x] + red_s[2][x] + red_s[3][x];
        mx = fmaxf(fmaxf(red_m[0][x], red_m[1][x]), fmaxf(red_m[2][x], red_m[3][x]));
        if (FIRST) {
            z[g * 768 + f] = s * invk;
            z[g * 768 + 256 + f] = mx;
            z[g * 768 + 512 + f] = s;
        } else {
            z[g * 768 + f] += s * invk;
            z[g * 768 + 256 + f] += mx;
            z[g * 768 + 512 + f] += s;
        }
    }
}

// ---------------- MLP ----------------
// fc1: grid NG*4, block = (g, 64-output chunk), 4-way k-split (192 each)
__global__ __launch_bounds__(256) void k_fc1(const float* __restrict__ z,
                                             const float* __restrict__ W1,
                                             const float* __restrict__ b1,
                                             float* __restrict__ t1) {
    __shared__ float zb[768];
    __shared__ float red[4][64];
    int g = blockIdx.x >> 2, oc = blockIdx.x & 3;
    int tid = threadIdx.x;
    zb[tid] = z[g * 768 + tid];
    zb[tid + 256] = z[g * 768 + 256 + tid];
    zb[tid + 512] = z[g * 768 + 512 + tid];
    __syncthreads();
    int x = tid & 63, y = tid >> 6;
    int col = oc * 64 + x;
    float s = 0.f;
    for (int i = y * 192; i < (y + 1) * 192; i++) s += zb[i] * W1[(size_t)i * 256 + col];
    red[y][x] = s;
    __syncthreads();
    if (y == 0) {
        float t = red[0][x] + red[1][x] + red[2][x] + red[3][x] + b1[col];
        t1[g * 256 + col] = fmaxf(t, 0.f);
    }
}

// fc2: grid NG*2, block = (g, 64-output chunk), 4-way k-split (64 each)
__global__ __launch_bounds__(256) void k_fc2(const float* __restrict__ t1,
                                             const float* __restrict__ W2,
                                             const float* __restrict__ b2,
                                             float* __restrict__ t2) {
    __shared__ float t1s[256];
    __shared__ float red[4][64];
    int g = blockIdx.x >> 1, oc = blockIdx.x & 1;
    int tid = threadIdx.x;
    t1s[tid] = t1[g * 256 + tid];
    __syncthreads();
    int x = tid & 63, y = tid >> 6;
    int col = oc * 64 + x;
    float s = 0.f;
    for (int i = y * 64; i < (y + 1) * 64; i++) s += t1s[i] * W2[(size_t)i * 128 + col];
    red[y][x] = s;
    __syncthreads();
    if (y == 0) {
        float t = ((red[0][x] + red[1][x]) + red[2][x]) + red[3][x] + b2[col];
        t2[g * 128 + col] = fmaxf(t, 0.f);
    }
}

// fc3 + log_softmax: grid NG
__global__ __launch_bounds__(256) void k_fc3(const float* __restrict__ t2,
                                             const float* __restrict__ W3,
                                             const float* __restrict__ b3,
                                             float* __restrict__ out) {
    __shared__ float t2s[128];
    __shared__ float t3[10];
    __shared__ float lse;
    int g = blockIdx.x, tid = threadIdx.x;
    if (tid < 128) t2s[tid] = t2[g * 128 + tid];
    __syncthreads();
    if (tid < 10) {
        float v = b3[tid];
        for (int i = 0; i < 128; i++) v += t2s[i] * W3[(size_t)i * 10 + tid];
        t3[tid] = v;
    }
    __syncthreads();
    if (tid == 0) {
        float m = t3[0];
        for (int c = 1; c < 10; c++) m = fmaxf(m, t3[c]);
        float se = 0.f;
        for (int c = 0; c < 10; c++) se += expf(t3[c] - m);
        lse = m + logf(se);
    }
    __syncthreads();
    if (tid < 10) out[g * 10 + tid] = t3[tid] - lse;
}

// ---------------- launcher ----------------
extern "C" void kernel_launch(void* const* d_in, const int* in_sizes, int n_in,
                              void* d_out, int out_size, void* d_ws, size_t ws_size,
                              hipStream_t stream) {
    const float* x        = (const float*)d_in[0];
    const int*   ei       = (const int*)d_in[1];
    const float* conv1_W  = (const float*)d_in[3];
    const float* conv1_b  = (const float*)d_in[4];
    const float* conv2_W  = (const float*)d_in[5];
    const float* conv2_b  = (const float*)d_in[6];
    const float* conv3_W  = (const float*)d_in[7];
    const float* conv3_b  = (const float*)d_in[8];
    const float* p1_relW  = (const float*)d_in[9];
    const float* p1_relb  = (const float*)d_in[10];
    const float* p1_rootW = (const float*)d_in[11];
    const float* p2_relW  = (const float*)d_in[12];
    const float* p2_relb  = (const float*)d_in[13];
    const float* p2_rootW = (const float*)d_in[14];
    const float* fc1_W    = (const float*)d_in[15];
    const float* fc1_b    = (const float*)d_in[16];
    const float* fc2_W    = (const float*)d_in[17];
    const float* fc2_b    = (const float*)d_in[18];
    const float* fc3_W    = (const float*)d_in[19];
    const float* fc3_b    = (const float*)d_in[20];
    float* out = (float*)d_out;

    const int E = in_sizes[1] / 2;
    const int EPG = E / NG;
    const int* e_src = ei;
    const int* e_dst = ei + E;

    // workspace layout
    char* base = (char*)d_ws;
    size_t off = 0;
    auto alloc = [&](size_t bytes) { size_t o = off; off = (off + bytes + 255) & ~(size_t)255; return o; };
    float* hW     = (float*)(base + alloc((size_t)NN * HDIM * 4));   // also xa (NN x FIN)
    float* hcur   = (float*)(base + alloc((size_t)NN * HDIM * 4));
    float* dis    = (float*)(base + alloc(NN * 4));
    float* r_rel  = (float*)(base + alloc(NN * 4));
    float* r_root = (float*)(base + alloc(NN * 4));
    float* rrel4  = (float*)(base + alloc((size_t)NN * 4 * 4));
    float* rroot4 = (float*)(base + alloc((size_t)NN * 4 * 4));
    int*   rowptr = (int*)(base + alloc((NN + 1) * 4));
    int*   csr    = (int*)(base + alloc((size_t)E * 4));
    float* wedge  = (float*)(base + alloc((size_t)E * 4));
    float* z      = (float*)(base + alloc((size_t)NG * 768 * 4));
    float* t1buf  = (float*)(base + alloc((size_t)NG * 256 * 4));
    float* t2buf  = (float*)(base + alloc((size_t)NG * 128 * 4));
    int*   list1  = (int*)(base + alloc((size_t)NG * 128 * 4));
    int*   list2  = (int*)(base + alloc((size_t)NG * 64 * 4));
    int*   list3  = (int*)(base + alloc((size_t)NG * 32 * 4));
    float* tans1  = (float*)(base + alloc((size_t)NG * 128 * 4));
    float* tans2  = (float*)(base + alloc((size_t)NG * 64 * 4));
    float* tans3  = (float*)(base + alloc((size_t)NG * 32 * 4));

    // CSR build (canonical sorted-by-src order => deterministic) + stage-1 wedge
    k_csr<<<NG, 256, 0, stream>>>(e_src, e_dst, EPG, rowptr, csr);
    k_sortw<<<NN * 64 / 256, 256, 0, stream>>>(rowptr, csr, wedge);

    float* xa = hW;

    // ---- stage 1 ----
    k_aggx<<<NN / 8, 256, 0, stream>>>(x, rowptr, csr, wedge, xa);
    {
        dim3 ggrid(HDIM / BN, NN / BM);
        k_sgemm<<<ggrid, 256, 0, stream>>>(xa, conv1_W, hcur, FIN, nullptr, conv1_b,
                                           p1_relW, p1_rootW, rrel4, rroot4);
    }
    k_topkf<true, true><<<NG, 256, 0, stream>>>(nullptr, rowptr, csr, nullptr, nullptr,
                                                rrel4, rroot4, p1_relb, 128,
                                                list1, tans1, dis, wedge);
    k_poolout2<true><<<NG * 4, 256, 0, stream>>>(hcur, tans1, list1, 128, 1.0f / 128.0f, z);

    // ---- stage 2 ----
    {
        dim3 ggrid(HDIM / BN, (NG * 128) / BM);
        k_sgemm<<<ggrid, 256, 0, stream>>>(hcur, conv2_W, hW, HDIM, list1, nullptr,
                                           nullptr, nullptr, nullptr, nullptr);
    }
    k_gcn_agg<<<(NG * 128) / 4, 256, 0, stream>>>(hW, dis, rowptr, csr, wedge, conv2_b,
                                                  list1, 32, p2_relW, p2_rootW,
                                                  hcur, r_rel, r_root);
    k_topkf<false, true><<<NG, 256, 0, stream>>>(dis, rowptr, csr, r_rel, r_root,
                                                 nullptr, nullptr, p2_relb, 64,
                                                 list2, tans2, dis, wedge);
    k_poolout2<false><<<NG * 4, 256, 0, stream>>>(hcur, tans2, list2, 64, 1.0f / 64.0f, z);

    // ---- stage 3 ----
    {
        dim3 ggrid(HDIM / BN, (NG * 64) / BM);
        k_sgemm<<<ggrid, 256, 0, stream>>>(hcur, conv3_W, hW, HDIM, list2, nullptr,
                                           nullptr, nullptr, nullptr, nullptr);
    }
    k_gcn_agg<<<(NG * 64) / 4, 256, 0, stream>>>(hW, dis, rowptr, csr, wedge, conv3_b,
                                                 list2, 16, p2_relW, p2_rootW,
                                                 hcur, r_rel, r_root);
    k_topkf<false, false><<<NG, 256, 0, stream>>>(dis, rowptr, csr, r_rel, r_root,
                                                  nullptr, nullptr, p2_relb, 32,
                                                  list3, tans3, nullptr, nullptr);
    k_poolout2<false><<<NG * 4, 256, 0, stream>>>(hcur, tans3, list3, 32, 1.0f / 32.0f, z);

    // ---- MLP ----
    k_fc1<<<NG * 4, 256, 0, stream>>>(z, fc1_W, fc1_b, t1buf);
    k_fc2<<<NG * 2, 256, 0, stream>>>(t1buf, fc2_W, fc2_b, t2buf);
    k_fc3<<<NG, 256, 0, stream>>>(t2buf, fc3_W, fc3_b, out);
}